// Round 6
// baseline (375.618 us; speedup 1.0000x reference)
//
#include <hip/hip_runtime.h>
#include <hip/hip_bf16.h>

typedef __attribute__((ext_vector_type(8))) short bh8;    // 8 x bf16 (4 VGPRs)
typedef __attribute__((ext_vector_type(4))) float f32x4;  // MFMA 16x16 accumulator

#define NB 8
#define SLOTS 64
#define CAP 8192      // per-k pair capacity (expected ~4760, sigma ~68)
#define CROWS 49152   // compact h2c rows (expected ~35000)
#define PPB 16
#define CBLOCKS 512   // persistent blocks for center_gemm (2/CU, 8 waves/CU)

// ---------------------------------------------------------------------------
// Layer 1: h1 = relu(subm_conv(feats, W1)) as bf16.
// ---------------------------------------------------------------------------
__global__ __launch_bounds__(256) void conv1_kernel(
    const float* __restrict__ feats, const float* __restrict__ W1,
    const int* __restrict__ nbr, __hip_bfloat16* __restrict__ h1b, int N) {
  __shared__ float W1s[27 * 256];
  __shared__ float fsT[27][16];
  __shared__ int s_nbr[PPB * 9];
  const int c = threadIdx.x;
  const int base = blockIdx.x * PPB;

  for (int t = c; t < 27 * 256; t += 256) W1s[t] = W1[t];
  if (c < PPB * 9) {
    int p = c / 9, k = c - p * 9;
    int gi = base + p;
    s_nbr[c] = (gi < N) ? nbr[gi * 9 + k] : -1;
  }
  __syncthreads();
  if (c < PPB * 9) {
    int p = c / 9, k = c - p * 9;
    int src = s_nbr[c];
    if (src >= 0) {
      fsT[k * 3 + 0][p] = feats[src * 3 + 0];
      fsT[k * 3 + 1][p] = feats[src * 3 + 1];
      fsT[k * 3 + 2][p] = feats[src * 3 + 2];
    } else {
      fsT[k * 3 + 0][p] = 0.f;
      fsT[k * 3 + 1][p] = 0.f;
      fsT[k * 3 + 2][p] = 0.f;
    }
  }
  __syncthreads();

  float acc[PPB];
#pragma unroll
  for (int p = 0; p < PPB; ++p) acc[p] = 0.f;

#pragma unroll 3
  for (int kj = 0; kj < 27; ++kj) {
    float w = W1s[kj * 256 + c];
    const float4* f4 = (const float4*)(&fsT[kj][0]);
    float4 fa = f4[0], fb = f4[1], fc = f4[2], fd = f4[3];
    acc[0]  += fa.x * w; acc[1]  += fa.y * w; acc[2]  += fa.z * w; acc[3]  += fa.w * w;
    acc[4]  += fb.x * w; acc[5]  += fb.y * w; acc[6]  += fb.z * w; acc[7]  += fb.w * w;
    acc[8]  += fc.x * w; acc[9]  += fc.y * w; acc[10] += fc.z * w; acc[11] += fc.w * w;
    acc[12] += fd.x * w; acc[13] += fd.y * w; acc[14] += fd.z * w; acc[15] += fd.w * w;
  }

#pragma unroll
  for (int p = 0; p < PPB; ++p) {
    int gi = base + p;
    if (gi < N) h1b[(long long)gi * 256 + c] = __float2bfloat16(fmaxf(acc[p], 0.f));
  }
}

// ---------------------------------------------------------------------------
// W2 fp32 [9][kk][n] -> bf16 transposed [9][n][kk].
// ---------------------------------------------------------------------------
__global__ __launch_bounds__(256) void w2t_kernel(
    const float* __restrict__ W2, __hip_bfloat16* __restrict__ w2bt) {
  __shared__ float tile[16][256];
  int k = blockIdx.x >> 4, t = blockIdx.x & 15;
  int tid = threadIdx.x;
#pragma unroll
  for (int r = 0; r < 16; ++r) tile[r][tid] = W2[k * 65536 + (t * 16 + r) * 256 + tid];
  __syncthreads();
#pragma unroll
  for (int r = 0; r < 16; ++r)
    w2bt[k * 65536 + tid * 256 + t * 16 + r] = __float2bfloat16(tile[r][tid]);
}

// ---------------------------------------------------------------------------
// Compaction with per-block aggregation (round-2 fix).
// ---------------------------------------------------------------------------
__global__ __launch_bounds__(256) void build_pairs_kernel(
    const int* __restrict__ nbr, const int* __restrict__ bid,
    int* __restrict__ nOff, int* __restrict__ cnt, float* __restrict__ bcnt,
    int* __restrict__ cidmap, int* __restrict__ psrc, int* __restrict__ pcid, int N) {
  __shared__ int l_cnt[10];
  __shared__ int l_base[10];
  __shared__ int l_bcnt[NB];
  const int tid = threadIdx.x;
  if (tid < 10) l_cnt[tid] = 0;
  if (tid < NB) l_bcnt[tid] = 0;
  __syncthreads();

  const int i = blockIdx.x * 256 + tid;
  const bool active = (i < N);
  int s[9];
  int kpos[9];
  int loc_cid = -1;
  if (active) {
#pragma unroll
    for (int k = 0; k < 9; ++k) s[k] = nbr[i * 9 + k];
    bool any = false;
#pragma unroll
    for (int k = 0; k < 9; ++k)
      if (k != 4 && s[k] >= 0) any = true;
    if (any) {
      loc_cid = atomicAdd(&l_cnt[9], 1);
#pragma unroll
      for (int k = 0; k < 9; ++k) {
        kpos[k] = -1;
        if (k != 4 && s[k] >= 0) kpos[k] = atomicAdd(&l_cnt[k], 1);
      }
    }
    atomicAdd(&l_bcnt[bid[i]], 1);
  }
  __syncthreads();

  if (tid < 9) l_base[tid] = (l_cnt[tid] > 0) ? atomicAdd(&cnt[tid], l_cnt[tid]) : 0;
  else if (tid == 9) l_base[9] = (l_cnt[9] > 0) ? atomicAdd(nOff, l_cnt[9]) : 0;
  if (tid >= 32 && tid < 32 + NB && l_bcnt[tid - 32] > 0)
    atomicAdd(&bcnt[tid - 32], (float)l_bcnt[tid - 32]);
  __syncthreads();

  if (active) {
    int cid = -1;
    if (loc_cid >= 0) {
      cid = l_base[9] + loc_cid;
      if (cid >= CROWS) cid = -1;
    }
    cidmap[i] = cid;
    if (cid >= 0) {
#pragma unroll
      for (int k = 0; k < 9; ++k) {
        if (k == 4 || kpos[k] < 0 || s[k] < 0) continue;
        int pos = l_base[k] + kpos[k];
        if (pos < CAP) {
          psrc[k * CAP + pos] = s[k];
          pcid[k * CAP + pos] = cid;
        }
      }
    }
  }
}

// ---------------------------------------------------------------------------
// Off-center taps: per (k, 16-row tile) gathered GEMM 16x256x256 bf16 MFMA,
// atomicAdd fp32 into compact h2c rows.
// ---------------------------------------------------------------------------
__global__ __launch_bounds__(256) void off_gemm_kernel(
    const __hip_bfloat16* __restrict__ h1, const __hip_bfloat16* __restrict__ w2bt,
    const int* __restrict__ cnt, const int* __restrict__ psrc,
    const int* __restrict__ pcid, float* __restrict__ h2c) {
  int koff = blockIdx.x >> 9;
  int tile = blockIdx.x & 511;
  int k = koff + (koff >= 4 ? 1 : 0);
  int cntk = cnt[k];
  if (tile * 16 >= cntk) return;

  __shared__ int s_src[16], s_cid[16];
  int tid = threadIdx.x;
  if (tid < 16) {
    int m = tile * 16 + tid;
    bool valid = m < cntk;
    s_src[tid] = valid ? psrc[k * CAP + m] : 0;
    s_cid[tid] = valid ? pcid[k * CAP + m] : -1;
  }
  __syncthreads();

  int wave = tid >> 6, lane = tid & 63, q = lane >> 4, m16 = lane & 15;
  const short* h1s = (const short*)h1;
  const short* wts = (const short*)w2bt + k * 65536;
  int srow = s_src[m16];

  bh8 aA[8];
#pragma unroll
  for (int ko = 0; ko < 8; ++ko)
    aA[ko] = *(const bh8*)(h1s + (long long)srow * 256 + ko * 32 + q * 8);

  f32x4 acc[4];
#pragma unroll
  for (int nj = 0; nj < 4; ++nj) acc[nj] = (f32x4)0.f;

#pragma unroll
  for (int ko = 0; ko < 8; ++ko) {
#pragma unroll
    for (int nj = 0; nj < 4; ++nj) {
      bh8 b = *(const bh8*)(wts + (wave * 64 + nj * 16 + m16) * 256 + ko * 32 + q * 8);
      acc[nj] = __builtin_amdgcn_mfma_f32_16x16x32_bf16(aA[ko], b, acc[nj], 0, 0, 0);
    }
  }
#pragma unroll
  for (int r = 0; r < 4; ++r) {
    int cid = s_cid[q * 4 + r];
    if (cid < 0) continue;
#pragma unroll
    for (int nj = 0; nj < 4; ++nj)
      atomicAdd(&h2c[(long long)cid * 256 + wave * 64 + nj * 16 + m16], acc[nj][r]);
  }
}

// ---------------------------------------------------------------------------
// Center tap dense GEMM h1 @ W2[4] fused with +h2c, ReLU, per-batch col sums.
// Round-6 rewrite: B ENTIRELY IN REGISTERS (wave owns 64 cols: 32 bh8 = 128
// VGPR), no LDS, no barriers. 512 persistent blocks x 4 waves; wave = 64-row
// chunks x its 64 cols, grid-stride over chunks. A double-buffered with
// next-chunk prefetch issued before the epilogue. Round-5 failure: 132 KB
// LDS -> 1 block/CU + 8-way LDS phase conflicts; everything serialized.
// ---------------------------------------------------------------------------
__global__ __launch_bounds__(256, 2) void center_gemm_kernel(
    const __hip_bfloat16* __restrict__ h1, const __hip_bfloat16* __restrict__ w2bt,
    const float* __restrict__ h2c, const int* __restrict__ cidmap,
    const int* __restrict__ bid, float* __restrict__ psums, int N) {
  const int tid = threadIdx.x;
  const int wave = tid >> 6, lane = tid & 63;
  const int q = lane >> 4, m16 = lane & 15;
  const int wc = wave << 6;  // this wave's 64-column slice

  const short* h1s = (const short*)h1;
  const short* wts = (const short*)w2bt + 4 * 65536;  // center tap, [n][kk]

  // B slice in registers: breg[nj][ko] = B[k=ko*32+q*8 ..][n=wc+nj*16+m16]
  bh8 breg[4][8];
#pragma unroll
  for (int nj = 0; nj < 4; ++nj)
#pragma unroll
    for (int ko = 0; ko < 8; ++ko)
      breg[nj][ko] = *(const bh8*)(wts + (wc + nj * 16 + m16) * 256 + ko * 32 + q * 8);

  const int nchunk = (N + 63) >> 6;
  int c = blockIdx.x;
  if (c >= nchunk) return;

  const short* abase[4];
#pragma unroll
  for (int mi = 0; mi < 4; ++mi) {
    int r = c * 64 + mi * 16 + m16;
    abase[mi] = h1s + (long long)((r < N) ? r : (N - 1)) * 256 + q * 8;
  }
  bh8 aA[2][4];
#pragma unroll
  for (int mi = 0; mi < 4; ++mi) aA[0][mi] = *(const bh8*)(abase[mi]);

  while (c < nchunk) {
    const int cn = c + CBLOCKS;
    const int cnc = (cn < nchunk) ? cn : c;  // safe prefetch target

    f32x4 acc[4][4];
    // ko = 0 (peeled): prefetch ko=1, MFMA with C=0
#pragma unroll
    for (int mi = 0; mi < 4; ++mi) aA[1][mi] = *(const bh8*)(abase[mi] + 32);
#pragma unroll
    for (int mi = 0; mi < 4; ++mi)
#pragma unroll
      for (int nj = 0; nj < 4; ++nj)
        acc[mi][nj] = __builtin_amdgcn_mfma_f32_16x16x32_bf16(aA[0][mi], breg[nj][0], (f32x4)0.f, 0, 0, 0);

#pragma unroll
    for (int ko = 1; ko < 8; ++ko) {
      const int cur = ko & 1;
      if (ko < 7) {
#pragma unroll
        for (int mi = 0; mi < 4; ++mi)
          aA[cur ^ 1][mi] = *(const bh8*)(abase[mi] + (ko + 1) * 32);
      } else {
        // prefetch NEXT chunk's ko=0 into aA[0] (parity: next peel reads aA[0])
#pragma unroll
        for (int mi = 0; mi < 4; ++mi) {
          int r = cnc * 64 + mi * 16 + m16;
          abase[mi] = h1s + (long long)((r < N) ? r : (N - 1)) * 256 + q * 8;
          aA[0][mi] = *(const bh8*)(abase[mi]);
        }
      }
#pragma unroll
      for (int mi = 0; mi < 4; ++mi)
#pragma unroll
        for (int nj = 0; nj < 4; ++nj)
          acc[mi][nj] = __builtin_amdgcn_mfma_f32_16x16x32_bf16(aA[cur][mi], breg[nj][ko], acc[mi][nj], 0, 0, 0);
    }

    // ---- epilogue for chunk c: + h2c, ReLU, per-batch column sums ----
    {
      const int r0 = c * 64;
      const int b0 = bid[r0];
      const int rlast = (r0 + 63 < N) ? r0 + 63 : N - 1;
      const bool mixed = (bid[rlast] != b0);

      float sacc[2][4];
#pragma unroll
      for (int lb = 0; lb < 2; ++lb)
#pragma unroll
        for (int nj = 0; nj < 4; ++nj) sacc[lb][nj] = 0.f;

#pragma unroll
      for (int mi = 0; mi < 4; ++mi) {
        const int rb = r0 + mi * 16 + q * 4;  // C/D row = q*4+rr (N%64==0: in-range)
        int4 b4 = *(const int4*)(&bid[rb]);
        int4 c4 = *(const int4*)(&cidmap[rb]);
        const int bb[4] = {b4.x, b4.y, b4.z, b4.w};
        const int cc[4] = {c4.x, c4.y, c4.z, c4.w};
#pragma unroll
        for (int rr = 0; rr < 4; ++rr) {
          if (rb + rr >= N) continue;
          const int cid = cc[rr];
          const int lb = (bb[rr] != b0) ? 1 : 0;
#pragma unroll
          for (int nj = 0; nj < 4; ++nj) {
            float v = acc[mi][nj][rr];
            if (cid >= 0) v += h2c[(long long)cid * 256 + wc + nj * 16 + m16];
            v = fmaxf(v, 0.f);
            sacc[lb][nj] += v;
          }
        }
      }
      const int slot = c & (SLOTS - 1);
#pragma unroll
      for (int lb = 0; lb < 2; ++lb) {
        if (lb == 1 && !mixed) continue;
#pragma unroll
        for (int nj = 0; nj < 4; ++nj) {
          float v = sacc[lb][nj];
          v += __shfl_xor(v, 16, 64);
          v += __shfl_xor(v, 32, 64);
          if (q == 0) {
            int b = b0 + lb;
            if (b < NB)
              atomicAdd(&psums[(slot * NB + b) * 256 + wc + nj * 16 + m16], v);
          }
        }
      }
    }
    c = cn;
  }
}

__global__ void finalize_kernel(const float* __restrict__ psums,
                                const float* __restrict__ bcnt,
                                float* __restrict__ out) {
  int b = blockIdx.x, c = threadIdx.x;
  float s = 0.f;
  for (int t = 0; t < SLOTS; ++t) s += psums[(t * NB + b) * 256 + c];
  out[b * 256 + c] = s / bcnt[b];
}

extern "C" void kernel_launch(void* const* d_in, const int* in_sizes, int n_in,
                              void* d_out, int out_size, void* d_ws, size_t ws_size,
                              hipStream_t stream) {
  const float* feats = (const float*)d_in[0];
  const float* W1    = (const float*)d_in[1];
  const float* W2    = (const float*)d_in[2];
  const int*   nbr   = (const int*)d_in[3];
  const int*   bid   = (const int*)d_in[4];
  float* out = (float*)d_out;
  const int N = in_sizes[0] / 3;

  // ---- workspace layout (256B-aligned segments) ----
  char* ws = (char*)d_ws;
  size_t o = 0;
  float* psums = (float*)(ws + o); o += (size_t)SLOTS * NB * 256 * 4;
  float* bcnt  = (float*)(ws + o); o += NB * 4;
  int*   nOff  = (int*)(ws + o);   o += 4;
  int*   cnt   = (int*)(ws + o);   o += 9 * 4;
  o = (o + 255) & ~(size_t)255;
  size_t zero1 = o;                         // memset [0, zero1)
  int* psrc = (int*)(ws + o); o += (size_t)9 * CAP * 4;
  int* pcid = (int*)(ws + o); o += (size_t)9 * CAP * 4;
  int* cidmap = (int*)(ws + o); o += (size_t)N * 4;
  o = (o + 255) & ~(size_t)255;
  float* h2c = (float*)(ws + o); o += (size_t)CROWS * 256 * 4;
  __hip_bfloat16* w2bt = (__hip_bfloat16*)(ws + o); o += (size_t)9 * 65536 * 2;
  __hip_bfloat16* h1b  = (__hip_bfloat16*)(ws + o); o += (size_t)N * 256 * 2;

  hipMemsetAsync(d_ws, 0, zero1, stream);
  hipMemsetAsync(h2c, 0, (size_t)CROWS * 256 * 4, stream);

  conv1_kernel<<<(N + PPB - 1) / PPB, 256, 0, stream>>>(feats, W1, nbr, h1b, N);
  w2t_kernel<<<9 * 16, 256, 0, stream>>>(W2, w2bt);
  build_pairs_kernel<<<(N + 255) / 256, 256, 0, stream>>>(nbr, bid, nOff, cnt, bcnt,
                                                          cidmap, psrc, pcid, N);
  off_gemm_kernel<<<8 * 512, 256, 0, stream>>>(h1b, w2bt, cnt, psrc, pcid, h2c);
  center_gemm_kernel<<<CBLOCKS, 256, 0, stream>>>(h1b, w2bt, h2c,
                                                  cidmap, bid, psums, N);
  finalize_kernel<<<NB, 256, 0, stream>>>(psums, bcnt, out);
}

// Round 7
// 366.830 us; speedup vs baseline: 1.0240x; 1.0240x over previous
//
#include <hip/hip_runtime.h>
#include <hip/hip_bf16.h>

typedef __attribute__((ext_vector_type(8))) short bh8;    // 8 x bf16 (4 VGPRs)
typedef __attribute__((ext_vector_type(4))) float f32x4;  // MFMA 16x16 accumulator

#define NB 8
#define SLOTS 64
#define CAP 8192      // per-k pair capacity (expected ~4760, sigma ~68)
#define CROWS 49152   // compact h2c rows (expected ~35000)
#define PPB 16
#define CBLOCKS 512   // persistent blocks for center_gemm (2/CU)

// async 16B global -> LDS DMA (no VGPR roundtrip); LDS dest is
// wave-uniform base + lane*16, global src is per-lane.
__device__ __forceinline__ void gld_lds16(const void* g, void* l) {
  __builtin_amdgcn_global_load_lds(
      (const __attribute__((address_space(1))) void*)g,
      (__attribute__((address_space(3))) void*)l, 16, 0, 0);
}

// ---------------------------------------------------------------------------
// Layer 1: h1 = relu(subm_conv(feats, W1)) as bf16.
// ---------------------------------------------------------------------------
__global__ __launch_bounds__(256) void conv1_kernel(
    const float* __restrict__ feats, const float* __restrict__ W1,
    const int* __restrict__ nbr, __hip_bfloat16* __restrict__ h1b, int N) {
  __shared__ float W1s[27 * 256];
  __shared__ float fsT[27][16];
  __shared__ int s_nbr[PPB * 9];
  const int c = threadIdx.x;
  const int base = blockIdx.x * PPB;

  for (int t = c; t < 27 * 256; t += 256) W1s[t] = W1[t];
  if (c < PPB * 9) {
    int p = c / 9, k = c - p * 9;
    int gi = base + p;
    s_nbr[c] = (gi < N) ? nbr[gi * 9 + k] : -1;
  }
  __syncthreads();
  if (c < PPB * 9) {
    int p = c / 9, k = c - p * 9;
    int src = s_nbr[c];
    if (src >= 0) {
      fsT[k * 3 + 0][p] = feats[src * 3 + 0];
      fsT[k * 3 + 1][p] = feats[src * 3 + 1];
      fsT[k * 3 + 2][p] = feats[src * 3 + 2];
    } else {
      fsT[k * 3 + 0][p] = 0.f;
      fsT[k * 3 + 1][p] = 0.f;
      fsT[k * 3 + 2][p] = 0.f;
    }
  }
  __syncthreads();

  float acc[PPB];
#pragma unroll
  for (int p = 0; p < PPB; ++p) acc[p] = 0.f;

#pragma unroll 3
  for (int kj = 0; kj < 27; ++kj) {
    float w = W1s[kj * 256 + c];
    const float4* f4 = (const float4*)(&fsT[kj][0]);
    float4 fa = f4[0], fb = f4[1], fc = f4[2], fd = f4[3];
    acc[0]  += fa.x * w; acc[1]  += fa.y * w; acc[2]  += fa.z * w; acc[3]  += fa.w * w;
    acc[4]  += fb.x * w; acc[5]  += fb.y * w; acc[6]  += fb.z * w; acc[7]  += fb.w * w;
    acc[8]  += fc.x * w; acc[9]  += fc.y * w; acc[10] += fc.z * w; acc[11] += fc.w * w;
    acc[12] += fd.x * w; acc[13] += fd.y * w; acc[14] += fd.z * w; acc[15] += fd.w * w;
  }

#pragma unroll
  for (int p = 0; p < PPB; ++p) {
    int gi = base + p;
    if (gi < N) h1b[(long long)gi * 256 + c] = __float2bfloat16(fmaxf(acc[p], 0.f));
  }
}

// ---------------------------------------------------------------------------
// W2 fp32 [9][kk][n] -> bf16 transposed [9][n][kk].
// ---------------------------------------------------------------------------
__global__ __launch_bounds__(256) void w2t_kernel(
    const float* __restrict__ W2, __hip_bfloat16* __restrict__ w2bt) {
  __shared__ float tile[16][256];
  int k = blockIdx.x >> 4, t = blockIdx.x & 15;
  int tid = threadIdx.x;
#pragma unroll
  for (int r = 0; r < 16; ++r) tile[r][tid] = W2[k * 65536 + (t * 16 + r) * 256 + tid];
  __syncthreads();
#pragma unroll
  for (int r = 0; r < 16; ++r)
    w2bt[k * 65536 + tid * 256 + t * 16 + r] = __float2bfloat16(tile[r][tid]);
}

// ---------------------------------------------------------------------------
// Compaction with per-block aggregation (round-2 fix).
// ---------------------------------------------------------------------------
__global__ __launch_bounds__(256) void build_pairs_kernel(
    const int* __restrict__ nbr, const int* __restrict__ bid,
    int* __restrict__ nOff, int* __restrict__ cnt, float* __restrict__ bcnt,
    int* __restrict__ cidmap, int* __restrict__ psrc, int* __restrict__ pcid, int N) {
  __shared__ int l_cnt[10];
  __shared__ int l_base[10];
  __shared__ int l_bcnt[NB];
  const int tid = threadIdx.x;
  if (tid < 10) l_cnt[tid] = 0;
  if (tid < NB) l_bcnt[tid] = 0;
  __syncthreads();

  const int i = blockIdx.x * 256 + tid;
  const bool active = (i < N);
  int s[9];
  int kpos[9];
  int loc_cid = -1;
  if (active) {
#pragma unroll
    for (int k = 0; k < 9; ++k) s[k] = nbr[i * 9 + k];
    bool any = false;
#pragma unroll
    for (int k = 0; k < 9; ++k)
      if (k != 4 && s[k] >= 0) any = true;
    if (any) {
      loc_cid = atomicAdd(&l_cnt[9], 1);
#pragma unroll
      for (int k = 0; k < 9; ++k) {
        kpos[k] = -1;
        if (k != 4 && s[k] >= 0) kpos[k] = atomicAdd(&l_cnt[k], 1);
      }
    }
    atomicAdd(&l_bcnt[bid[i]], 1);
  }
  __syncthreads();

  if (tid < 9) l_base[tid] = (l_cnt[tid] > 0) ? atomicAdd(&cnt[tid], l_cnt[tid]) : 0;
  else if (tid == 9) l_base[9] = (l_cnt[9] > 0) ? atomicAdd(nOff, l_cnt[9]) : 0;
  if (tid >= 32 && tid < 32 + NB && l_bcnt[tid - 32] > 0)
    atomicAdd(&bcnt[tid - 32], (float)l_bcnt[tid - 32]);
  __syncthreads();

  if (active) {
    int cid = -1;
    if (loc_cid >= 0) {
      cid = l_base[9] + loc_cid;
      if (cid >= CROWS) cid = -1;
    }
    cidmap[i] = cid;
    if (cid >= 0) {
#pragma unroll
      for (int k = 0; k < 9; ++k) {
        if (k == 4 || kpos[k] < 0 || s[k] < 0) continue;
        int pos = l_base[k] + kpos[k];
        if (pos < CAP) {
          psrc[k * CAP + pos] = s[k];
          pcid[k * CAP + pos] = cid;
        }
      }
    }
  }
}

// ---------------------------------------------------------------------------
// Off-center taps: per (k, 16-row tile) gathered GEMM 16x256x256 bf16 MFMA,
// atomicAdd fp32 into compact h2c rows.
// ---------------------------------------------------------------------------
__global__ __launch_bounds__(256) void off_gemm_kernel(
    const __hip_bfloat16* __restrict__ h1, const __hip_bfloat16* __restrict__ w2bt,
    const int* __restrict__ cnt, const int* __restrict__ psrc,
    const int* __restrict__ pcid, float* __restrict__ h2c) {
  int koff = blockIdx.x >> 9;
  int tile = blockIdx.x & 511;
  int k = koff + (koff >= 4 ? 1 : 0);
  int cntk = cnt[k];
  if (tile * 16 >= cntk) return;

  __shared__ int s_src[16], s_cid[16];
  int tid = threadIdx.x;
  if (tid < 16) {
    int m = tile * 16 + tid;
    bool valid = m < cntk;
    s_src[tid] = valid ? psrc[k * CAP + m] : 0;
    s_cid[tid] = valid ? pcid[k * CAP + m] : -1;
  }
  __syncthreads();

  int wave = tid >> 6, lane = tid & 63, q = lane >> 4, m16 = lane & 15;
  const short* h1s = (const short*)h1;
  const short* wts = (const short*)w2bt + k * 65536;
  int srow = s_src[m16];

  bh8 aA[8];
#pragma unroll
  for (int ko = 0; ko < 8; ++ko)
    aA[ko] = *(const bh8*)(h1s + (long long)srow * 256 + ko * 32 + q * 8);

  f32x4 acc[4];
#pragma unroll
  for (int nj = 0; nj < 4; ++nj) acc[nj] = (f32x4)0.f;

#pragma unroll
  for (int ko = 0; ko < 8; ++ko) {
#pragma unroll
    for (int nj = 0; nj < 4; ++nj) {
      bh8 b = *(const bh8*)(wts + (wave * 64 + nj * 16 + m16) * 256 + ko * 32 + q * 8);
      acc[nj] = __builtin_amdgcn_mfma_f32_16x16x32_bf16(aA[ko], b, acc[nj], 0, 0, 0);
    }
  }
#pragma unroll
  for (int r = 0; r < 4; ++r) {
    int cid = s_cid[q * 4 + r];
    if (cid < 0) continue;
#pragma unroll
    for (int nj = 0; nj < 4; ++nj)
      atomicAdd(&h2c[(long long)cid * 256 + wave * 64 + nj * 16 + m16], acc[nj][r]);
  }
}

// ---------------------------------------------------------------------------
// Center tap dense GEMM h1 @ W2[4] fused with +h2c, ReLU, per-batch col sums.
// Round-7: LDS double-buffered A chunks (64 rows = 32 KB) staged via
// global_load_lds DMA (prefetch chunk c+512 while computing chunk c), B in
// registers, A read from LDS with XOR-by-row 16B-chunk swizzle (2-way bank
// access = free). Round-6 failure: 1-ko-deep register prefetch left ~4 loads
// in flight vs ~600cyc latency -> MfmaUtil 7%, 700 GB/s stream.
// ---------------------------------------------------------------------------
__global__ __launch_bounds__(256, 2) void center_gemm_kernel(
    const __hip_bfloat16* __restrict__ h1, const __hip_bfloat16* __restrict__ w2bt,
    const float* __restrict__ h2c, const int* __restrict__ cidmap,
    const int* __restrict__ bid, float* __restrict__ psums, int N) {
  __shared__ __align__(16) short Abuf[2][64 * 256];  // 2 x 32 KB

  const int tid = threadIdx.x;
  const int wave = tid >> 6, lane = tid & 63;
  const int q = lane >> 4, m16 = lane & 15;
  const int wc = wave << 6;  // this wave's 64-column slice

  const short* h1s = (const short*)h1;
  const short* wts = (const short*)w2bt + 4 * 65536;  // center tap, [n][kk]

  // B slice in registers: breg[nj][ko] = B[k=ko*32+q*8..][n=wc+nj*16+m16]
  bh8 breg[4][8];
#pragma unroll
  for (int nj = 0; nj < 4; ++nj)
#pragma unroll
    for (int ko = 0; ko < 8; ++ko)
      breg[nj][ko] = *(const bh8*)(wts + (wc + nj * 16 + m16) * 256 + ko * 32 + q * 8);

  const int nchunk = (N + 63) >> 6;
  int c = blockIdx.x;
  if (c >= nchunk) return;

  const int lrow = lane >> 5;      // staging: 0/1 (row within pair)
  const int jch  = lane & 31;      // staging: 16B chunk within row

  // stage chunk cc into Abuf[b]: LDS(row, chunk p) <- global chunk p^(row&31)
  // (swizzle folded into the per-lane global address; LDS side is the
  //  mandatory wave-uniform base + lane*16)
#define STAGE_CHUNK(cc, b)                                                     \
  {                                                                            \
    _Pragma("unroll") for (int t = 0; t < 8; ++t) {                            \
      int lr = (wave << 4) + (t << 1) + lrow;                                  \
      int g = ((cc) << 6) + lr;                                                \
      if (g >= N) g = N - 1;                                                   \
      int js = jch ^ (lr & 31);                                                \
      const short* src = h1s + (long long)g * 256 + (js << 3);                 \
      short* dst = &Abuf[b][((wave << 4) + (t << 1)) << 8];                    \
      gld_lds16((const void*)src, (void*)dst);                                 \
    }                                                                          \
  }

  STAGE_CHUNK(c, 0);
  int cur = 0;

  while (true) {
    __syncthreads();  // DMA into Abuf[cur] complete; prior reads of other buf done
    const int cn = c + CBLOCKS;
    if (cn < nchunk) STAGE_CHUNK(cn, cur ^ 1);

    // ---- compute chunk c from Abuf[cur] ----
    const short* Ab = &Abuf[cur][0];
    const short* abase[4];
    int xr[4];
#pragma unroll
    for (int mi = 0; mi < 4; ++mi) {
      int R = mi * 16 + m16;
      xr[mi] = R & 31;
      abase[mi] = Ab + (R << 8);
    }

    f32x4 acc[4][4];
#pragma unroll
    for (int ko = 0; ko < 8; ++ko) {
      bh8 a[4];
#pragma unroll
      for (int mi = 0; mi < 4; ++mi)
        a[mi] = *(const bh8*)(abase[mi] + (((ko * 4 + q) ^ xr[mi]) << 3));
#pragma unroll
      for (int mi = 0; mi < 4; ++mi)
#pragma unroll
        for (int nj = 0; nj < 4; ++nj)
          acc[mi][nj] = __builtin_amdgcn_mfma_f32_16x16x32_bf16(
              a[mi], breg[nj][ko], (ko == 0) ? (f32x4)0.f : acc[mi][nj], 0, 0, 0);
    }

    // ---- epilogue for chunk c: + h2c, ReLU, per-batch column sums ----
    {
      const int r0 = c << 6;
      const int b0 = bid[r0];
      const int rlast = (r0 + 63 < N) ? r0 + 63 : N - 1;
      const bool mixed = (bid[rlast] != b0);

      float sacc[2][4];
#pragma unroll
      for (int lb = 0; lb < 2; ++lb)
#pragma unroll
        for (int nj = 0; nj < 4; ++nj) sacc[lb][nj] = 0.f;

#pragma unroll
      for (int mi = 0; mi < 4; ++mi) {
        const int rb = r0 + mi * 16 + q * 4;  // C/D row = q*4+rr
        int4 b4 = *(const int4*)(&bid[rb]);
        int4 c4 = *(const int4*)(&cidmap[rb]);
        const int bb[4] = {b4.x, b4.y, b4.z, b4.w};
        const int cc4[4] = {c4.x, c4.y, c4.z, c4.w};
#pragma unroll
        for (int rr = 0; rr < 4; ++rr) {
          if (rb + rr >= N) continue;
          const int cid = cc4[rr];
          const int lb = (bb[rr] != b0) ? 1 : 0;
#pragma unroll
          for (int nj = 0; nj < 4; ++nj) {
            float v = acc[mi][nj][rr];
            if (cid >= 0) v += h2c[(long long)cid * 256 + wc + nj * 16 + m16];
            v = fmaxf(v, 0.f);
            sacc[lb][nj] += v;
          }
        }
      }
      const int slot = c & (SLOTS - 1);
#pragma unroll
      for (int lb = 0; lb < 2; ++lb) {
        if (lb == 1 && !mixed) continue;
#pragma unroll
        for (int nj = 0; nj < 4; ++nj) {
          float v = sacc[lb][nj];
          v += __shfl_xor(v, 16, 64);
          v += __shfl_xor(v, 32, 64);
          if (q == 0) {
            int b = b0 + lb;
            if (b < NB)
              atomicAdd(&psums[(slot * NB + b) * 256 + wc + nj * 16 + m16], v);
          }
        }
      }
    }

    if (cn >= nchunk) break;
    c = cn;
    cur ^= 1;
  }
#undef STAGE_CHUNK
}

__global__ void finalize_kernel(const float* __restrict__ psums,
                                const float* __restrict__ bcnt,
                                float* __restrict__ out) {
  int b = blockIdx.x, c = threadIdx.x;
  float s = 0.f;
  for (int t = 0; t < SLOTS; ++t) s += psums[(t * NB + b) * 256 + c];
  out[b * 256 + c] = s / bcnt[b];
}

extern "C" void kernel_launch(void* const* d_in, const int* in_sizes, int n_in,
                              void* d_out, int out_size, void* d_ws, size_t ws_size,
                              hipStream_t stream) {
  const float* feats = (const float*)d_in[0];
  const float* W1    = (const float*)d_in[1];
  const float* W2    = (const float*)d_in[2];
  const int*   nbr   = (const int*)d_in[3];
  const int*   bid   = (const int*)d_in[4];
  float* out = (float*)d_out;
  const int N = in_sizes[0] / 3;

  // ---- workspace layout (256B-aligned segments) ----
  char* ws = (char*)d_ws;
  size_t o = 0;
  float* psums = (float*)(ws + o); o += (size_t)SLOTS * NB * 256 * 4;
  float* bcnt  = (float*)(ws + o); o += NB * 4;
  int*   nOff  = (int*)(ws + o);   o += 4;
  int*   cnt   = (int*)(ws + o);   o += 9 * 4;
  o = (o + 255) & ~(size_t)255;
  size_t zero1 = o;                         // memset [0, zero1)
  int* psrc = (int*)(ws + o); o += (size_t)9 * CAP * 4;
  int* pcid = (int*)(ws + o); o += (size_t)9 * CAP * 4;
  int* cidmap = (int*)(ws + o); o += (size_t)N * 4;
  o = (o + 255) & ~(size_t)255;
  float* h2c = (float*)(ws + o); o += (size_t)CROWS * 256 * 4;
  __hip_bfloat16* w2bt = (__hip_bfloat16*)(ws + o); o += (size_t)9 * 65536 * 2;
  __hip_bfloat16* h1b  = (__hip_bfloat16*)(ws + o); o += (size_t)N * 256 * 2;

  hipMemsetAsync(d_ws, 0, zero1, stream);
  hipMemsetAsync(h2c, 0, (size_t)CROWS * 256 * 4, stream);

  conv1_kernel<<<(N + PPB - 1) / PPB, 256, 0, stream>>>(feats, W1, nbr, h1b, N);
  w2t_kernel<<<9 * 16, 256, 0, stream>>>(W2, w2bt);
  build_pairs_kernel<<<(N + 255) / 256, 256, 0, stream>>>(nbr, bid, nOff, cnt, bcnt,
                                                          cidmap, psrc, pcid, N);
  off_gemm_kernel<<<8 * 512, 256, 0, stream>>>(h1b, w2bt, cnt, psrc, pcid, h2c);
  center_gemm_kernel<<<CBLOCKS, 256, 0, stream>>>(h1b, w2bt, h2c,
                                                  cidmap, bid, psums, N);
  finalize_kernel<<<NB, 256, 0, stream>>>(psums, bcnt, out);
}

// Round 8
// 361.104 us; speedup vs baseline: 1.0402x; 1.0159x over previous
//
#include <hip/hip_runtime.h>
#include <hip/hip_bf16.h>

typedef __attribute__((ext_vector_type(8))) short bh8;    // 8 x bf16 (4 VGPRs)
typedef __attribute__((ext_vector_type(4))) float f32x4;  // MFMA 16x16 accumulator

#define NB 8
#define SLOTS 64
#define CAP 8192      // per-k pair capacity (expected ~4760, sigma ~68)
#define CROWS 40960   // compact h2c rows (expected ~35000 +- 170)
#define PPB 16
#define CBLOCKS 512   // persistent blocks for center_gemm (2/CU)
#define RG 4          // chunks per reduce block

// async 16B global -> LDS DMA; LDS dest = wave-uniform base + lane*16.
__device__ __forceinline__ void gld_lds16(const void* g, void* l) {
  __builtin_amdgcn_global_load_lds(
      (const __attribute__((address_space(1))) void*)g,
      (__attribute__((address_space(3))) void*)l, 16, 0, 0);
}

__device__ __forceinline__ unsigned short f2bu(float f) {
  union { __hip_bfloat16 h; unsigned short u; } cv;
  cv.h = __float2bfloat16(f);
  return cv.u;
}
__device__ __forceinline__ float bu2f(unsigned short u) {
  return __uint_as_float(((unsigned)u) << 16);
}

// ---------------------------------------------------------------------------
// Layer 1: h1 = relu(subm_conv(feats, W1)) as bf16.
// ---------------------------------------------------------------------------
__global__ __launch_bounds__(256) void conv1_kernel(
    const float* __restrict__ feats, const float* __restrict__ W1,
    const int* __restrict__ nbr, __hip_bfloat16* __restrict__ h1b, int N) {
  __shared__ float W1s[27 * 256];
  __shared__ float fsT[27][16];
  __shared__ int s_nbr[PPB * 9];
  const int c = threadIdx.x;
  const int base = blockIdx.x * PPB;

  for (int t = c; t < 27 * 256; t += 256) W1s[t] = W1[t];
  if (c < PPB * 9) {
    int p = c / 9, k = c - p * 9;
    int gi = base + p;
    s_nbr[c] = (gi < N) ? nbr[gi * 9 + k] : -1;
  }
  __syncthreads();
  if (c < PPB * 9) {
    int p = c / 9, k = c - p * 9;
    int src = s_nbr[c];
    if (src >= 0) {
      fsT[k * 3 + 0][p] = feats[src * 3 + 0];
      fsT[k * 3 + 1][p] = feats[src * 3 + 1];
      fsT[k * 3 + 2][p] = feats[src * 3 + 2];
    } else {
      fsT[k * 3 + 0][p] = 0.f;
      fsT[k * 3 + 1][p] = 0.f;
      fsT[k * 3 + 2][p] = 0.f;
    }
  }
  __syncthreads();

  float acc[PPB];
#pragma unroll
  for (int p = 0; p < PPB; ++p) acc[p] = 0.f;

#pragma unroll 3
  for (int kj = 0; kj < 27; ++kj) {
    float w = W1s[kj * 256 + c];
    const float4* f4 = (const float4*)(&fsT[kj][0]);
    float4 fa = f4[0], fb = f4[1], fc = f4[2], fd = f4[3];
    acc[0]  += fa.x * w; acc[1]  += fa.y * w; acc[2]  += fa.z * w; acc[3]  += fa.w * w;
    acc[4]  += fb.x * w; acc[5]  += fb.y * w; acc[6]  += fb.z * w; acc[7]  += fb.w * w;
    acc[8]  += fc.x * w; acc[9]  += fc.y * w; acc[10] += fc.z * w; acc[11] += fc.w * w;
    acc[12] += fd.x * w; acc[13] += fd.y * w; acc[14] += fd.z * w; acc[15] += fd.w * w;
  }

#pragma unroll
  for (int p = 0; p < PPB; ++p) {
    int gi = base + p;
    if (gi < N) h1b[(long long)gi * 256 + c] = __float2bfloat16(fmaxf(acc[p], 0.f));
  }
}

// ---------------------------------------------------------------------------
// W2 fp32 [9][kk][n] -> bf16 transposed [9][n][kk].
// ---------------------------------------------------------------------------
__global__ __launch_bounds__(256) void w2t_kernel(
    const float* __restrict__ W2, __hip_bfloat16* __restrict__ w2bt) {
  __shared__ float tile[16][256];
  int k = blockIdx.x >> 4, t = blockIdx.x & 15;
  int tid = threadIdx.x;
#pragma unroll
  for (int r = 0; r < 16; ++r) tile[r][tid] = W2[k * 65536 + (t * 16 + r) * 256 + tid];
  __syncthreads();
#pragma unroll
  for (int r = 0; r < 16; ++r)
    w2bt[k * 65536 + tid * 256 + t * 16 + r] = __float2bfloat16(tile[r][tid]);
}

// ---------------------------------------------------------------------------
// Compaction with per-block aggregation (round-2 fix).
// ---------------------------------------------------------------------------
__global__ __launch_bounds__(256) void build_pairs_kernel(
    const int* __restrict__ nbr, const int* __restrict__ bid,
    int* __restrict__ nOff, int* __restrict__ cnt, float* __restrict__ bcnt,
    int* __restrict__ cidmap, int* __restrict__ psrc, int* __restrict__ pcid, int N) {
  __shared__ int l_cnt[10];
  __shared__ int l_base[10];
  __shared__ int l_bcnt[NB];
  const int tid = threadIdx.x;
  if (tid < 10) l_cnt[tid] = 0;
  if (tid < NB) l_bcnt[tid] = 0;
  __syncthreads();

  const int i = blockIdx.x * 256 + tid;
  const bool active = (i < N);
  int s[9];
  int kpos[9];
  int loc_cid = -1;
  if (active) {
#pragma unroll
    for (int k = 0; k < 9; ++k) s[k] = nbr[i * 9 + k];
    bool any = false;
#pragma unroll
    for (int k = 0; k < 9; ++k)
      if (k != 4 && s[k] >= 0) any = true;
    if (any) {
      loc_cid = atomicAdd(&l_cnt[9], 1);
#pragma unroll
      for (int k = 0; k < 9; ++k) {
        kpos[k] = -1;
        if (k != 4 && s[k] >= 0) kpos[k] = atomicAdd(&l_cnt[k], 1);
      }
    }
    atomicAdd(&l_bcnt[bid[i]], 1);
  }
  __syncthreads();

  if (tid < 9) l_base[tid] = (l_cnt[tid] > 0) ? atomicAdd(&cnt[tid], l_cnt[tid]) : 0;
  else if (tid == 9) l_base[9] = (l_cnt[9] > 0) ? atomicAdd(nOff, l_cnt[9]) : 0;
  if (tid >= 32 && tid < 32 + NB && l_bcnt[tid - 32] > 0)
    atomicAdd(&bcnt[tid - 32], (float)l_bcnt[tid - 32]);
  __syncthreads();

  if (active) {
    int cid = -1;
    if (loc_cid >= 0) {
      cid = l_base[9] + loc_cid;
      if (cid >= CROWS) cid = -1;
    }
    cidmap[i] = cid;
    if (cid >= 0) {
#pragma unroll
      for (int k = 0; k < 9; ++k) {
        if (k == 4 || kpos[k] < 0 || s[k] < 0) continue;
        int pos = l_base[k] + kpos[k];
        if (pos < CAP) {
          psrc[k * CAP + pos] = s[k];
          pcid[k * CAP + pos] = cid;
        }
      }
    }
  }
}

// ---------------------------------------------------------------------------
// Off-center taps: per (k, 16-row tile) gathered GEMM 16x256x256 bf16 MFMA,
// atomicAdd fp32 into compact h2c rows.
// ---------------------------------------------------------------------------
__global__ __launch_bounds__(256) void off_gemm_kernel(
    const __hip_bfloat16* __restrict__ h1, const __hip_bfloat16* __restrict__ w2bt,
    const int* __restrict__ cnt, const int* __restrict__ psrc,
    const int* __restrict__ pcid, float* __restrict__ h2c) {
  int koff = blockIdx.x >> 9;
  int tile = blockIdx.x & 511;
  int k = koff + (koff >= 4 ? 1 : 0);
  int cntk = cnt[k];
  if (tile * 16 >= cntk) return;

  __shared__ int s_src[16], s_cid[16];
  int tid = threadIdx.x;
  if (tid < 16) {
    int m = tile * 16 + tid;
    bool valid = m < cntk;
    s_src[tid] = valid ? psrc[k * CAP + m] : 0;
    s_cid[tid] = valid ? pcid[k * CAP + m] : -1;
  }
  __syncthreads();

  int wave = tid >> 6, lane = tid & 63, q = lane >> 4, m16 = lane & 15;
  const short* h1s = (const short*)h1;
  const short* wts = (const short*)w2bt + k * 65536;
  int srow = s_src[m16];

  bh8 aA[8];
#pragma unroll
  for (int ko = 0; ko < 8; ++ko)
    aA[ko] = *(const bh8*)(h1s + (long long)srow * 256 + ko * 32 + q * 8);

  f32x4 acc[4];
#pragma unroll
  for (int nj = 0; nj < 4; ++nj) acc[nj] = (f32x4)0.f;

#pragma unroll
  for (int ko = 0; ko < 8; ++ko) {
#pragma unroll
    for (int nj = 0; nj < 4; ++nj) {
      bh8 b = *(const bh8*)(wts + (wave * 64 + nj * 16 + m16) * 256 + ko * 32 + q * 8);
      acc[nj] = __builtin_amdgcn_mfma_f32_16x16x32_bf16(aA[ko], b, acc[nj], 0, 0, 0);
    }
  }
#pragma unroll
  for (int r = 0; r < 4; ++r) {
    int cid = s_cid[q * 4 + r];
    if (cid < 0) continue;
#pragma unroll
    for (int nj = 0; nj < 4; ++nj)
      atomicAdd(&h2c[(long long)cid * 256 + wave * 64 + nj * 16 + m16], acc[nj][r]);
  }
}

// ---------------------------------------------------------------------------
// Center tap dense GEMM h1 @ W2[4] — PURE (round-8): no fused epilogue.
// Same DMA+LDS dbuf + register-B pipeline as round 7, but the only output is
// 16 coalesced ushort4 stores per lane of the bf16 accumulator in its natural
// (permuted) layout, written IN-PLACE over h1 (chunk c's h1 rows are consumed
// only by chunk c, before the store). No scattered loads, no atomics, no
// vmcnt-coupled dependent chains -> the prefetch overlap finally works.
// Round-7 failure: epilogue loads/atomics after the DMA burst drained the
// prefetch queue (vmcnt FIFO) + device-scope psums atomic hot-spotting,
// serialized ~50k cyc/iter.
// Permuted layout: seg = ((c*4 + wave)*16 + mi*4 + nj) -> 64 lanes x 8 B;
// element (seg, lane, rr) = C[row = c*64+mi*16+(lane>>4)*4+rr]
//                            [col = wave*64+nj*16+(lane&15)].
// ---------------------------------------------------------------------------
__global__ __launch_bounds__(256, 2) void center_gemm_kernel(
    __hip_bfloat16* h1io, const __hip_bfloat16* __restrict__ w2bt, int N) {
  __shared__ __align__(16) short Abuf[2][64 * 256];  // 2 x 32 KB

  const int tid = threadIdx.x;
  const int wave = tid >> 6, lane = tid & 63;
  const int q = lane >> 4, m16 = lane & 15;
  const int wc = wave << 6;

  const short* h1s = (const short*)h1io;
  const short* wts = (const short*)w2bt + 4 * 65536;  // center tap, [n][kk]

  bh8 breg[4][8];
#pragma unroll
  for (int nj = 0; nj < 4; ++nj)
#pragma unroll
    for (int ko = 0; ko < 8; ++ko)
      breg[nj][ko] = *(const bh8*)(wts + (wc + nj * 16 + m16) * 256 + ko * 32 + q * 8);

  const int nchunk = (N + 63) >> 6;
  int c = blockIdx.x;
  if (c >= nchunk) return;

  const int lrow = lane >> 5;
  const int jch  = lane & 31;

#define STAGE_CHUNK(cc, b)                                                     \
  {                                                                            \
    _Pragma("unroll") for (int t = 0; t < 8; ++t) {                            \
      int lr = (wave << 4) + (t << 1) + lrow;                                  \
      int g = ((cc) << 6) + lr;                                                \
      if (g >= N) g = N - 1;                                                   \
      int js = jch ^ (lr & 31);                                                \
      const short* src = h1s + (long long)g * 256 + (js << 3);                 \
      short* dst = &Abuf[b][((wave << 4) + (t << 1)) << 8];                    \
      gld_lds16((const void*)src, (void*)dst);                                 \
    }                                                                          \
  }

  STAGE_CHUNK(c, 0);
  int cur = 0;
  ushort4* outp = (ushort4*)h1io;

  while (true) {
    __syncthreads();  // DMA into Abuf[cur] complete
    const int cn = c + CBLOCKS;
    if (cn < nchunk) STAGE_CHUNK(cn, cur ^ 1);

    // ---- compute chunk c from Abuf[cur] ----
    const short* Ab = &Abuf[cur][0];
    const short* abase[4];
    int xr[4];
#pragma unroll
    for (int mi = 0; mi < 4; ++mi) {
      int R = mi * 16 + m16;
      xr[mi] = R & 31;
      abase[mi] = Ab + (R << 8);
    }

    f32x4 acc[4][4];
#pragma unroll
    for (int ko = 0; ko < 8; ++ko) {
      bh8 a[4];
#pragma unroll
      for (int mi = 0; mi < 4; ++mi)
        a[mi] = *(const bh8*)(abase[mi] + (((ko * 4 + q) ^ xr[mi]) << 3));
#pragma unroll
      for (int mi = 0; mi < 4; ++mi)
#pragma unroll
        for (int nj = 0; nj < 4; ++nj)
          acc[mi][nj] = __builtin_amdgcn_mfma_f32_16x16x32_bf16(
              a[mi], breg[nj][ko], (ko == 0) ? (f32x4)0.f : acc[mi][nj], 0, 0, 0);
    }

    // ---- store: bf16, permuted layout, in-place over h1 chunk c ----
    {
      const long long segbase = ((long long)c * 4 + wave) * 16;
#pragma unroll
      for (int mi = 0; mi < 4; ++mi)
#pragma unroll
        for (int nj = 0; nj < 4; ++nj) {
          f32x4 v = acc[mi][nj];
          ushort4 u;
          u.x = f2bu(v[0]); u.y = f2bu(v[1]); u.z = f2bu(v[2]); u.w = f2bu(v[3]);
          outp[(segbase + mi * 4 + nj) * 64 + lane] = u;
        }
    }

    if (cn >= nchunk) break;
    c = cn;
    cur ^= 1;
  }
#undef STAGE_CHUNK
}

// ---------------------------------------------------------------------------
// Reduce: read permuted bf16 h2 (in-place in h1), merge off-center partials
// (h2c via cidmap), ReLU, per-batch column sums -> slotted psums. Register
// accumulation across RG chunks, one flush per block. Pure streaming.
// ---------------------------------------------------------------------------
__global__ __launch_bounds__(256) void reduce_kernel(
    const __hip_bfloat16* __restrict__ h2pb, const float* __restrict__ h2c,
    const int* __restrict__ cidmap, const int* __restrict__ bid,
    float* __restrict__ psums, int N) {
  const int tid = threadIdx.x;
  const int sw = tid >> 6, lane = tid & 63;
  const int q = lane >> 4, m16 = lane & 15;
  const int nchunk = (N + 63) >> 6;
  const int c0 = blockIdx.x * RG;
  if (c0 >= nchunk) return;
  const ushort4* hp = (const ushort4*)h2pb;
  const int b0 = bid[c0 << 6];

  float sacc[2][4];
#pragma unroll
  for (int lb = 0; lb < 2; ++lb)
#pragma unroll
    for (int nj = 0; nj < 4; ++nj) sacc[lb][nj] = 0.f;

  for (int g = 0; g < RG; ++g) {
    const int cc = c0 + g;
    if (cc >= nchunk) break;
#pragma unroll
    for (int mi = 0; mi < 4; ++mi) {
      const int rb = (cc << 6) + mi * 16 + q * 4;
      int4 b4 = *(const int4*)(&bid[rb]);
      int4 c4 = *(const int4*)(&cidmap[rb]);
      const int bb[4] = {b4.x, b4.y, b4.z, b4.w};
      const int cc4[4] = {c4.x, c4.y, c4.z, c4.w};
#pragma unroll
      for (int nj = 0; nj < 4; ++nj) {
        ushort4 u = hp[((long long)cc * 4 + sw) * 16 * 64 + (mi * 4 + nj) * 64 + lane];
        const float v[4] = {bu2f(u.x), bu2f(u.y), bu2f(u.z), bu2f(u.w)};
        const int col = sw * 64 + nj * 16 + m16;
#pragma unroll
        for (int rr = 0; rr < 4; ++rr) {
          if (rb + rr >= N) continue;
          float x = v[rr];
          const int cid = cc4[rr];
          if (cid >= 0) x += h2c[(long long)cid * 256 + col];
          x = fmaxf(x, 0.f);
          sacc[(bb[rr] != b0) ? 1 : 0][nj] += x;
        }
      }
    }
  }

  int rlast = (c0 + RG) << 6;
  rlast = ((rlast < N) ? rlast : N) - 1;
  const bool mixed = (bid[rlast] != b0);
  const int slot = blockIdx.x & (SLOTS - 1);
#pragma unroll
  for (int lb = 0; lb < 2; ++lb) {
    if (lb == 1 && !mixed) continue;
#pragma unroll
    for (int nj = 0; nj < 4; ++nj) {
      float v = sacc[lb][nj];
      v += __shfl_xor(v, 16, 64);
      v += __shfl_xor(v, 32, 64);
      if (q == 0) {
        int b = b0 + lb;
        if (b < NB)
          atomicAdd(&psums[(slot * NB + b) * 256 + sw * 64 + nj * 16 + m16], v);
      }
    }
  }
}

__global__ void finalize_kernel(const float* __restrict__ psums,
                                const float* __restrict__ bcnt,
                                float* __restrict__ out) {
  int b = blockIdx.x, c = threadIdx.x;
  float s = 0.f;
  for (int t = 0; t < SLOTS; ++t) s += psums[(t * NB + b) * 256 + c];
  out[b * 256 + c] = s / bcnt[b];
}

extern "C" void kernel_launch(void* const* d_in, const int* in_sizes, int n_in,
                              void* d_out, int out_size, void* d_ws, size_t ws_size,
                              hipStream_t stream) {
  const float* feats = (const float*)d_in[0];
  const float* W1    = (const float*)d_in[1];
  const float* W2    = (const float*)d_in[2];
  const int*   nbr   = (const int*)d_in[3];
  const int*   bid   = (const int*)d_in[4];
  float* out = (float*)d_out;
  const int N = in_sizes[0] / 3;

  // ---- workspace layout (256B-aligned segments) ----
  char* ws = (char*)d_ws;
  size_t o = 0;
  float* psums = (float*)(ws + o); o += (size_t)SLOTS * NB * 256 * 4;
  float* bcnt  = (float*)(ws + o); o += NB * 4;
  int*   nOff  = (int*)(ws + o);   o += 4;
  int*   cnt   = (int*)(ws + o);   o += 9 * 4;
  o = (o + 255) & ~(size_t)255;
  size_t zero1 = o;                         // memset [0, zero1)
  int* psrc = (int*)(ws + o); o += (size_t)9 * CAP * 4;
  int* pcid = (int*)(ws + o); o += (size_t)9 * CAP * 4;
  int* cidmap = (int*)(ws + o); o += (size_t)N * 4;
  o = (o + 255) & ~(size_t)255;
  float* h2c = (float*)(ws + o); o += (size_t)CROWS * 256 * 4;
  __hip_bfloat16* w2bt = (__hip_bfloat16*)(ws + o); o += (size_t)9 * 65536 * 2;
  __hip_bfloat16* h1b  = (__hip_bfloat16*)(ws + o); o += (size_t)N * 256 * 2;

  hipMemsetAsync(d_ws, 0, zero1, stream);
  hipMemsetAsync(h2c, 0, (size_t)CROWS * 256 * 4, stream);

  conv1_kernel<<<(N + PPB - 1) / PPB, 256, 0, stream>>>(feats, W1, nbr, h1b, N);
  w2t_kernel<<<9 * 16, 256, 0, stream>>>(W2, w2bt);
  build_pairs_kernel<<<(N + 255) / 256, 256, 0, stream>>>(nbr, bid, nOff, cnt, bcnt,
                                                          cidmap, psrc, pcid, N);
  off_gemm_kernel<<<8 * 512, 256, 0, stream>>>(h1b, w2bt, cnt, psrc, pcid, h2c);
  center_gemm_kernel<<<CBLOCKS, 256, 0, stream>>>(h1b, w2bt, N);
  const int nchunk = (N + 63) / 64;
  reduce_kernel<<<(nchunk + RG - 1) / RG, 256, 0, stream>>>(h1b, h2c, cidmap, bid,
                                                            psums, N);
  finalize_kernel<<<NB, 256, 0, stream>>>(psums, bcnt, out);
}